// Round 11
// baseline (729.282 us; speedup 1.0000x reference)
//
#include <hip/hip_runtime.h>

#define TSTEPS 20
#define THRESV 1.0f
#define DECAYV 0.9375f

typedef float f32x4 __attribute__((ext_vector_type(4)));

// ws byte layout:
//   [0,      7680)   u64 s_in_bits[20][48]
//   [7680,  28160)   u64 s1_bits[20][128]
//   [28160, 48640)   u64 s2_bits[20][128]
//   [48640, 48720)   u32 cnt1[20]   (memset to 0 each launch)
//   [48720, 48800)   u32 cnt2[20]   (memset to 0 each launch)

__global__ void snn_input_kernel(const float* __restrict__ image,
                                 unsigned long long* __restrict__ s_in_bits) {
    int i = blockIdx.x * 256 + threadIdx.x;   // 0..3071
    float img = image[i];
    float mi = 0.f;
    int word = i >> 6, lane = i & 63;
    for (int t = 0; t < TSTEPS; ++t) {
        mi += img;
        bool fire = (mi >= THRESV);
        if (fire) mi -= THRESV;
        unsigned long long bm = __ballot(fire);
        if (lane == 0) s_in_bits[t * 48 + word] = bm;
    }
}

struct __align__(16) SMem {
    unsigned short list[8192];      // 16 KiB compacted firing-row indices
    float partials[2048];           // 8 KiB  [32 groups][64 cols]
    unsigned long long bw[128];     // bitmask snapshot
    unsigned pc[128];               // per-word popcounts
    int cntp;
    float mcol[64];                 // persistent membrane slice
};

__device__ __forceinline__ void wait_cnt(const unsigned* p, unsigned target) {
    if (threadIdx.x == 0) {
        while (__hip_atomic_load(p, __ATOMIC_ACQUIRE, __HIP_MEMORY_SCOPE_AGENT) < target)
            __builtin_amdgcn_s_sleep(16);
    }
    __syncthreads();
}

// Deterministic parallel compaction: 8 waves each own NW/8 words; ascending
// list order identical to all passing rounds => bitwise-identical sums.
template <int NW>
__device__ __forceinline__ int compact_par(const unsigned long long* bits, SMem& sm) {
    int tid = threadIdx.x;
    if (tid < NW) {
        unsigned long long w = __hip_atomic_load(&bits[tid], __ATOMIC_RELAXED, __HIP_MEMORY_SCOPE_AGENT);
        sm.bw[tid] = w;
        sm.pc[tid] = (unsigned)__popcll(w);
    }
    __syncthreads();
    constexpr int WPW = NW / 8;
    int wave = tid >> 6, lane = tid & 63;
    int w0 = wave * WPW;
    int base = 0;
    for (int i = lane; i < w0; i += 64) base += (int)sm.pc[i];
    #pragma unroll
    for (int off = 1; off < 64; off <<= 1) base += __shfl_xor(base, off);
    if (wave == 0) {
        int tot = 0;
        for (int i = lane; i < NW; i += 64) tot += (int)sm.pc[i];
        #pragma unroll
        for (int off = 1; off < 64; off <<= 1) tot += __shfl_xor(tot, off);
        if (lane == 0) sm.cntp = tot;
    }
    for (int i = 0; i < WPW; ++i) {
        unsigned long long w = sm.bw[w0 + i];
        if ((w >> lane) & 1ull) {
            int pos = base + __popcll(w & ((1ull << lane) - 1ull));
            sm.list[pos] = (unsigned short)(((w0 + i) << 6) + lane);
        }
        base += __popcll(w);
    }
    __syncthreads();
    return sm.cntp;
}

#define GLD(dst, ptr) \
    asm volatile("global_load_dwordx4 %0, %1, off" : "=v"(dst) : "v"(ptr))
#define WAIT8(a0,a1,a2,a3,a4,a5,a6,a7) \
    asm volatile("s_waitcnt vmcnt(0)" \
        : "+v"(a0),"+v"(a1),"+v"(a2),"+v"(a3),"+v"(a4),"+v"(a5),"+v"(a6),"+v"(a7))

// 64-column gather + LIF epilogue. Main loop: 8 global_load_dwordx4 forced
// in flight via inline asm (register deps the scheduler cannot collapse).
// Per-thread FP-add order = ascending k = g, g+32, g+64, ... -> identical
// chain to all passing rounds => bitwise-identical sums.
__device__ __forceinline__ void gather_lif64(const float* __restrict__ W, int colbase,
                                             int count, SMem& sm,
                                             unsigned long long* dst_word,
                                             unsigned* cnt_pub) {
    int tid = threadIdx.x;
    int c = tid & 15, g = tid >> 4;
    const float* base = W + (size_t)colbase + (size_t)c * 4;
    float ax = 0.f, ay = 0.f, az = 0.f, aw = 0.f;
    int k = g;
    for (; k + 224 < count; k += 256) {              // forced 8-deep
        const float* p0 = base + (size_t)sm.list[k      ] * 8192;
        const float* p1 = base + (size_t)sm.list[k + 32 ] * 8192;
        const float* p2 = base + (size_t)sm.list[k + 64 ] * 8192;
        const float* p3 = base + (size_t)sm.list[k + 96 ] * 8192;
        const float* p4 = base + (size_t)sm.list[k + 128] * 8192;
        const float* p5 = base + (size_t)sm.list[k + 160] * 8192;
        const float* p6 = base + (size_t)sm.list[k + 192] * 8192;
        const float* p7 = base + (size_t)sm.list[k + 224] * 8192;
        f32x4 a0, a1, a2, a3, a4, a5, a6, a7;
        GLD(a0, p0); GLD(a1, p1); GLD(a2, p2); GLD(a3, p3);
        GLD(a4, p4); GLD(a5, p5); GLD(a6, p6); GLD(a7, p7);
        WAIT8(a0, a1, a2, a3, a4, a5, a6, a7);
        ax += a0.x; ay += a0.y; az += a0.z; aw += a0.w;
        ax += a1.x; ay += a1.y; az += a1.z; aw += a1.w;
        ax += a2.x; ay += a2.y; az += a2.z; aw += a2.w;
        ax += a3.x; ay += a3.y; az += a3.z; aw += a3.w;
        ax += a4.x; ay += a4.y; az += a4.z; aw += a4.w;
        ax += a5.x; ay += a5.y; az += a5.z; aw += a5.w;
        ax += a6.x; ay += a6.y; az += a6.z; aw += a6.w;
        ax += a7.x; ay += a7.y; az += a7.z; aw += a7.w;
    }
    for (; k + 96 < count; k += 128) {               // 4-deep mid tail
        f32x4 v0 = *(const f32x4*)(base + (size_t)sm.list[k     ] * 8192);
        f32x4 v1 = *(const f32x4*)(base + (size_t)sm.list[k + 32] * 8192);
        f32x4 v2 = *(const f32x4*)(base + (size_t)sm.list[k + 64] * 8192);
        f32x4 v3 = *(const f32x4*)(base + (size_t)sm.list[k + 96] * 8192);
        ax += v0.x; ay += v0.y; az += v0.z; aw += v0.w;
        ax += v1.x; ay += v1.y; az += v1.z; aw += v1.w;
        ax += v2.x; ay += v2.y; az += v2.z; aw += v2.w;
        ax += v3.x; ay += v3.y; az += v3.z; aw += v3.w;
    }
    for (; k < count; k += 32) {
        f32x4 v = *(const f32x4*)(base + (size_t)sm.list[k] * 8192);
        ax += v.x; ay += v.y; az += v.z; aw += v.w;
    }
    ((f32x4*)sm.partials)[g * 16 + c] = (f32x4){ax, ay, az, aw};
    __syncthreads();

    if (tid < 64) {  // wave 0: one lane per column, fixed ascending order
        float s = 0.f;
        #pragma unroll
        for (int gg = 0; gg < 32; ++gg) s += sm.partials[gg * 64 + tid];
        float v = sm.mcol[tid] + s;
        bool fire = (v >= THRESV);
        if (fire) v -= THRESV;
        sm.mcol[tid] = fire ? v : v * DECAYV;
        unsigned long long bm = __ballot(fire);
        if (tid == 0) {
            __hip_atomic_store(dst_word, bm, __ATOMIC_RELEASE, __HIP_MEMORY_SCOPE_AGENT);
            __hip_atomic_fetch_add(cnt_pub, 1u, __ATOMIC_RELEASE, __HIP_MEMORY_SCOPE_AGENT);
        }
    }
    __syncthreads();
}

__global__ void __launch_bounds__(512, 1)
snn_persistent(const float* __restrict__ W1, const float* __restrict__ W2,
               const float* __restrict__ W3,
               const unsigned long long* __restrict__ s_in_bits,
               unsigned long long* __restrict__ s1_bits,
               unsigned long long* __restrict__ s2_bits,
               unsigned* __restrict__ cnt1, unsigned* __restrict__ cnt2,
               float* __restrict__ out) {
    __shared__ SMem sm;
    int tid = threadIdx.x;
    int b = blockIdx.x;
    if (tid < 64) sm.mcol[tid] = 0.f;
    __syncthreads();

    if (b < 128) {
        // ---- layer-1 role: depends only on precomputed input spikes ----
        for (int t = 0; t < TSTEPS; ++t) {
            int count = compact_par<48>(s_in_bits + (size_t)t * 48, sm);
            gather_lif64(W1, b * 64, count, sm, &s1_bits[t * 128 + b], &cnt1[t]);
        }
    } else if (b < 256) {
        // ---- layer-2 role: consumes s1[t-1] ----
        int cb = b - 128;
        if (tid == 0) {   // step 0: zero input -> no fire, membrane stays 0
            __hip_atomic_store(&s2_bits[cb], 0ull, __ATOMIC_RELEASE, __HIP_MEMORY_SCOPE_AGENT);
            __hip_atomic_fetch_add(&cnt2[0], 1u, __ATOMIC_RELEASE, __HIP_MEMORY_SCOPE_AGENT);
        }
        for (int t = 1; t < TSTEPS; ++t) {
            wait_cnt(&cnt1[t - 1], 128);
            int count = compact_par<128>(s1_bits + (size_t)(t - 1) * 128, sm);
            gather_lif64(W2, cb * 64, count, sm, &s2_bits[t * 128 + cb], &cnt2[t]);
        }
    } else {
        // ---- layer-3 role (single block): consumes s2[t-1] ----
        if (tid < 10) { out[tid] = 0.f; out[10 + tid] = 0.f; }  // rows 0,1
        for (int t = 1; t < TSTEPS; ++t) {
            wait_cnt(&cnt2[t - 1], 128);
            int count = compact_par<128>(s2_bits + (size_t)(t - 1) * 128, sm);
            int col = tid & 15, g = tid >> 4;                    // 32 groups
            float acc = 0.f;
            if (col < 10) {
                for (int k = g; k < count; k += 32)
                    acc += W3[(size_t)sm.list[k] * 10 + col];
            }
            sm.partials[g * 16 + col] = acc;
            __syncthreads();
            if (tid < 10) {
                float s = 0.f;
                for (int gg = 0; gg < 32; ++gg) s += sm.partials[gg * 16 + tid];
                float v = sm.mcol[tid] + s;
                bool fire = (v >= THRESV);
                if (fire) v -= THRESV;
                sm.mcol[tid] = fire ? v : v * DECAYV;
                out[(t + 1) * 10 + tid] = fire ? 1.f : 0.f;
            }
            __syncthreads();
        }
    }
}

extern "C" void kernel_launch(void* const* d_in, const int* in_sizes, int n_in,
                              void* d_out, int out_size, void* d_ws, size_t ws_size,
                              hipStream_t stream) {
    const float* image = (const float*)d_in[0];
    const float* W1 = (const float*)d_in[1];
    const float* W2 = (const float*)d_in[2];
    const float* W3 = (const float*)d_in[3];
    float* out = (float*)d_out;

    char* ws = (char*)d_ws;
    unsigned long long* s_in_bits = (unsigned long long*)ws;            // [20][48]
    unsigned long long* s1_bits = (unsigned long long*)(ws + 7680);     // [20][128]
    unsigned long long* s2_bits = (unsigned long long*)(ws + 28160);    // [20][128]
    unsigned* cnt1 = (unsigned*)(ws + 48640);                           // [20]
    unsigned* cnt2 = (unsigned*)(ws + 48720);                           // [20]

    // counters must be zero before the persistent kernel starts (each replay)
    hipMemsetAsync(ws + 48640, 0, 160, stream);

    snn_input_kernel<<<12, 256, 0, stream>>>(image, s_in_bits);

    snn_persistent<<<257, 512, 0, stream>>>(W1, W2, W3, s_in_bits,
                                            s1_bits, s2_bits, cnt1, cnt2, out);
}

// Round 12
// 460.754 us; speedup vs baseline: 1.5828x; 1.5828x over previous
//
#include <hip/hip_runtime.h>

#define TSTEPS 20
#define THRESV 1.0f
#define DECAYV 0.9375f

typedef float f32x4 __attribute__((ext_vector_type(4)));

// ws layout (bytes):
//   [0      .. 32768)   float m1[8192]
//   [32768  .. 65536)   float m2[8192]
//   [65536  .. 65600)   float m3[16]
//   [65600  .. 73280)   u64 s_in_bits[20][48]
//   [73280  .. 93760)   u64 s1_bits[20][128]
//   [93760  .. 114240)  u64 s2_bits[20][128]

__global__ void snn_input_kernel(const float* __restrict__ image,
                                 unsigned long long* __restrict__ s_in_bits) {
    int i = blockIdx.x * 256 + threadIdx.x;   // 0..3071
    float img = image[i];
    float mi = 0.f;
    int word = i >> 6, lane = i & 63;
    for (int t = 0; t < TSTEPS; ++t) {
        mi += img;
        bool fire = (mi >= THRESV);
        if (fire) mi -= THRESV;
        unsigned long long bm = __ballot(fire);
        if (lane == 0) s_in_bits[t * 48 + word] = bm;
    }
}

struct __align__(16) SMem {
    unsigned short list[8192];      // 16 KiB compacted firing-row indices
    float partials[4096];           // 16 KiB (W1: [32][64]; W2: [32][128])
    unsigned long long bw[128];
    unsigned pc[128];
    int cntp;
};

// Deterministic parallel compaction: 8 waves each own NW/8 words; ascending
// list order identical to all passing rounds => bitwise-identical sums.
template <int NW>
__device__ __forceinline__ int compact_par(const unsigned long long* bits, SMem& sm) {
    int tid = threadIdx.x;
    if (tid < NW) {
        unsigned long long w = bits ? bits[tid] : 0ULL;
        sm.bw[tid] = w;
        sm.pc[tid] = (unsigned)__popcll(w);
    }
    __syncthreads();
    constexpr int WPW = NW / 8;
    int wave = tid >> 6, lane = tid & 63;
    int w0 = wave * WPW;
    int base = 0;
    for (int i = lane; i < w0; i += 64) base += (int)sm.pc[i];
    #pragma unroll
    for (int off = 1; off < 64; off <<= 1) base += __shfl_xor(base, off);
    if (wave == 0) {
        int tot = 0;
        for (int i = lane; i < NW; i += 64) tot += (int)sm.pc[i];
        #pragma unroll
        for (int off = 1; off < 64; off <<= 1) tot += __shfl_xor(tot, off);
        if (lane == 0) sm.cntp = tot;
    }
    for (int i = 0; i < WPW; ++i) {
        unsigned long long w = sm.bw[w0 + i];
        if ((w >> lane) & 1ull) {
            int pos = base + __popcll(w & ((1ull << lane) - 1ull));
            sm.list[pos] = (unsigned short)(((w0 + i) << 6) + lane);
        }
        base += __popcll(w);
    }
    __syncthreads();
    return sm.cntp;
}

#define GLD(dst, ptr) \
    asm volatile("global_load_dwordx4 %0, %1, off" : "=v"(dst) : "v"(ptr))
#define WAIT8(a0,a1,a2,a3,a4,a5,a6,a7) \
    asm volatile("s_waitcnt vmcnt(0)" \
        : "+v"(a0),"+v"(a1),"+v"(a2),"+v"(a3),"+v"(a4),"+v"(a5),"+v"(a6),"+v"(a7))
#define WAIT4(a0,a1,a2,a3) \
    asm volatile("s_waitcnt vmcnt(0)" : "+v"(a0),"+v"(a1),"+v"(a2),"+v"(a3))

// ---- W1 path: 64-col slice, 256B chunks, forced 8-deep (r10 verbatim) ----
__device__ __forceinline__ void gather_lif64(const float* __restrict__ W, int colbase,
                                             int count, SMem& sm,
                                             float* __restrict__ m, int mbase,
                                             unsigned long long* __restrict__ dst_word) {
    int tid = threadIdx.x;
    int c = tid & 15, g = tid >> 4;
    const float* base = W + (size_t)colbase + (size_t)c * 4;
    float ax = 0.f, ay = 0.f, az = 0.f, aw = 0.f;
    int k = g;
    for (; k + 224 < count; k += 256) {
        const float* p0 = base + (size_t)sm.list[k      ] * 8192;
        const float* p1 = base + (size_t)sm.list[k + 32 ] * 8192;
        const float* p2 = base + (size_t)sm.list[k + 64 ] * 8192;
        const float* p3 = base + (size_t)sm.list[k + 96 ] * 8192;
        const float* p4 = base + (size_t)sm.list[k + 128] * 8192;
        const float* p5 = base + (size_t)sm.list[k + 160] * 8192;
        const float* p6 = base + (size_t)sm.list[k + 192] * 8192;
        const float* p7 = base + (size_t)sm.list[k + 224] * 8192;
        f32x4 a0, a1, a2, a3, a4, a5, a6, a7;
        GLD(a0, p0); GLD(a1, p1); GLD(a2, p2); GLD(a3, p3);
        GLD(a4, p4); GLD(a5, p5); GLD(a6, p6); GLD(a7, p7);
        WAIT8(a0, a1, a2, a3, a4, a5, a6, a7);
        ax += a0.x; ay += a0.y; az += a0.z; aw += a0.w;
        ax += a1.x; ay += a1.y; az += a1.z; aw += a1.w;
        ax += a2.x; ay += a2.y; az += a2.z; aw += a2.w;
        ax += a3.x; ay += a3.y; az += a3.z; aw += a3.w;
        ax += a4.x; ay += a4.y; az += a4.z; aw += a4.w;
        ax += a5.x; ay += a5.y; az += a5.z; aw += a5.w;
        ax += a6.x; ay += a6.y; az += a6.z; aw += a6.w;
        ax += a7.x; ay += a7.y; az += a7.z; aw += a7.w;
    }
    for (; k + 96 < count; k += 128) {
        f32x4 v0 = *(const f32x4*)(base + (size_t)sm.list[k     ] * 8192);
        f32x4 v1 = *(const f32x4*)(base + (size_t)sm.list[k + 32] * 8192);
        f32x4 v2 = *(const f32x4*)(base + (size_t)sm.list[k + 64] * 8192);
        f32x4 v3 = *(const f32x4*)(base + (size_t)sm.list[k + 96] * 8192);
        ax += v0.x; ay += v0.y; az += v0.z; aw += v0.w;
        ax += v1.x; ay += v1.y; az += v1.z; aw += v1.w;
        ax += v2.x; ay += v2.y; az += v2.z; aw += v2.w;
        ax += v3.x; ay += v3.y; az += v3.z; aw += v3.w;
    }
    for (; k < count; k += 32) {
        f32x4 v = *(const f32x4*)(base + (size_t)sm.list[k] * 8192);
        ax += v.x; ay += v.y; az += v.z; aw += v.w;
    }
    ((f32x4*)sm.partials)[g * 16 + c] = (f32x4){ax, ay, az, aw};
    __syncthreads();

    if (tid < 64) {
        float s = 0.f;
        #pragma unroll
        for (int gg = 0; gg < 32; ++gg) s += sm.partials[gg * 64 + tid];
        int j = mbase + tid;
        float v = m[j] + s;
        bool fire = (v >= THRESV);
        if (fire) v -= THRESV;
        m[j] = fire ? v : v * DECAYV;
        unsigned long long bm = __ballot(fire);
        if (tid == 0) *dst_word = bm;
    }
}

// ---- W2 path: 128-col slice, 512B chunks, dual chains (g and g+16), each
// chain's add order = ascending k (bitwise-identical partials to r2 chain).
__device__ __forceinline__ void gather_lif128(const float* __restrict__ W, int colbase,
                                              int count, SMem& sm,
                                              float* __restrict__ m, int mbase,
                                              unsigned long long* __restrict__ dst_words) {
    int tid = threadIdx.x;
    int c = tid & 31, g = tid >> 5;                  // c 0..31, g 0..15
    const float* base = W + (size_t)colbase + (size_t)c * 4;
    float ax = 0.f, ay = 0.f, az = 0.f, aw = 0.f;    // chain A (group g)
    float bx = 0.f, by = 0.f, bz = 0.f, bw_ = 0.f;   // chain B (group g+16)
    int k = g;
    for (; k + 112 < count; k += 128) {              // A: k,k+32,k+64,k+96  B: +16 each
        const float* pa0 = base + (size_t)sm.list[k      ] * 8192;
        const float* pa1 = base + (size_t)sm.list[k + 32 ] * 8192;
        const float* pa2 = base + (size_t)sm.list[k + 64 ] * 8192;
        const float* pa3 = base + (size_t)sm.list[k + 96 ] * 8192;
        const float* pb0 = base + (size_t)sm.list[k + 16 ] * 8192;
        const float* pb1 = base + (size_t)sm.list[k + 48 ] * 8192;
        const float* pb2 = base + (size_t)sm.list[k + 80 ] * 8192;
        const float* pb3 = base + (size_t)sm.list[k + 112] * 8192;
        f32x4 a0, a1, a2, a3, b0, b1, b2, b3;
        GLD(a0, pa0); GLD(b0, pb0); GLD(a1, pa1); GLD(b1, pb1);
        GLD(a2, pa2); GLD(b2, pb2); GLD(a3, pa3); GLD(b3, pb3);
        WAIT8(a0, b0, a1, b1, a2, b2, a3, b3);
        ax += a0.x; ay += a0.y; az += a0.z; aw += a0.w;
        ax += a1.x; ay += a1.y; az += a1.z; aw += a1.w;
        ax += a2.x; ay += a2.y; az += a2.z; aw += a2.w;
        ax += a3.x; ay += a3.y; az += a3.z; aw += a3.w;
        bx += b0.x; by += b0.y; bz += b0.z; bw_ += b0.w;
        bx += b1.x; by += b1.y; bz += b1.z; bw_ += b1.w;
        bx += b2.x; by += b2.y; bz += b2.z; bw_ += b2.w;
        bx += b3.x; by += b3.y; bz += b3.z; bw_ += b3.w;
    }
    for (; k + 48 < count; k += 64) {                // A: k,k+32  B: k+16,k+48
        const float* pa0 = base + (size_t)sm.list[k     ] * 8192;
        const float* pa1 = base + (size_t)sm.list[k + 32] * 8192;
        const float* pb0 = base + (size_t)sm.list[k + 16] * 8192;
        const float* pb1 = base + (size_t)sm.list[k + 48] * 8192;
        f32x4 a0, a1, b0, b1;
        GLD(a0, pa0); GLD(b0, pb0); GLD(a1, pa1); GLD(b1, pb1);
        WAIT4(a0, b0, a1, b1);
        ax += a0.x; ay += a0.y; az += a0.z; aw += a0.w;
        ax += a1.x; ay += a1.y; az += a1.z; aw += a1.w;
        bx += b0.x; by += b0.y; bz += b0.z; bw_ += b0.w;
        bx += b1.x; by += b1.y; bz += b1.z; bw_ += b1.w;
    }
    for (; k < count; k += 32) {                     // A: k   B: k+16 (guarded)
        f32x4 va = *(const f32x4*)(base + (size_t)sm.list[k] * 8192);
        ax += va.x; ay += va.y; az += va.z; aw += va.w;
        if (k + 16 < count) {
            f32x4 vb = *(const f32x4*)(base + (size_t)sm.list[k + 16] * 8192);
            bx += vb.x; by += vb.y; bz += vb.z; bw_ += vb.w;
        }
    }
    ((f32x4*)sm.partials)[g * 32 + c] = (f32x4){ax, ay, az, aw};          // group g
    ((f32x4*)sm.partials)[(g + 16) * 32 + c] = (f32x4){bx, by, bz, bw_};  // group g+16
    __syncthreads();

    if (tid < 128) {   // two waves: one lane per column, ascending group order
        float s = 0.f;
        #pragma unroll
        for (int gg = 0; gg < 32; ++gg) s += sm.partials[gg * 128 + tid];
        int j = mbase + tid;
        float v = m[j] + s;
        bool fire = (v >= THRESV);
        if (fire) v -= THRESV;
        m[j] = fire ? v : v * DECAYV;
        unsigned long long bm = __ballot(fire);      // per-wave (64 lanes)
        if ((tid & 63) == 0) dst_words[tid >> 6] = bm;
    }
}

__global__ void __launch_bounds__(512)
snn_step_kernel(const float* __restrict__ W1, const float* __restrict__ W2,
                const float* __restrict__ W3,
                float* __restrict__ m1, float* __restrict__ m2, float* __restrict__ m3,
                const unsigned long long* __restrict__ sin_b,
                const unsigned long long* __restrict__ s1p_b,
                const unsigned long long* __restrict__ s2p_b,
                unsigned long long* __restrict__ s1_out,
                unsigned long long* __restrict__ s2_out,
                float* __restrict__ out_row) {
    __shared__ SMem sm;
    int b = blockIdx.x;
    int tid = threadIdx.x;
    if (b < 128) {
        int count = compact_par<48>(sin_b, sm);
        gather_lif64(W1, b * 64, count, sm, m1, b * 64, &s1_out[b]);
    } else if (b < 192) {
        int cb = b - 128;                            // 64 slices x 128 cols
        int count = compact_par<128>(s1p_b, sm);
        gather_lif128(W2, cb * 128, count, sm, m2, cb * 128, &s2_out[2 * cb]);
    } else {
        // layer 3: 10 outputs, W3 is 8192x10. 32 groups x 16 cols.
        int count = compact_par<128>(s2p_b, sm);
        int col = tid & 15, g = tid >> 4;            // g 0..31
        float acc = 0.f;
        if (col < 10) {
            for (int k = g; k < count; k += 32)
                acc += W3[(size_t)sm.list[k] * 10 + col];
        }
        sm.partials[g * 16 + col] = acc;
        __syncthreads();
        if (tid < 10) {
            float s = 0.f;
            for (int gg = 0; gg < 32; ++gg) s += sm.partials[gg * 16 + tid];
            float v = m3[tid] + s;
            bool fire = (v >= THRESV);
            if (fire) v -= THRESV;
            m3[tid] = fire ? v : v * DECAYV;
            out_row[tid] = fire ? 1.f : 0.f;
        }
    }
}

extern "C" void kernel_launch(void* const* d_in, const int* in_sizes, int n_in,
                              void* d_out, int out_size, void* d_ws, size_t ws_size,
                              hipStream_t stream) {
    const float* image = (const float*)d_in[0];
    const float* W1 = (const float*)d_in[1];
    const float* W2 = (const float*)d_in[2];
    const float* W3 = (const float*)d_in[3];
    float* out = (float*)d_out;

    char* ws = (char*)d_ws;
    float* m1 = (float*)ws;
    float* m2 = m1 + 8192;
    float* m3 = m2 + 8192;  // 16 floats
    unsigned long long* s_in_bits = (unsigned long long*)(ws + 65600);   // [20][48]
    unsigned long long* s1_bits = s_in_bits + TSTEPS * 48;               // [20][128]
    unsigned long long* s2_bits = s1_bits + TSTEPS * 128;                // [20][128]

    // zero membranes + output (harness poisons both; state must reset every launch)
    hipMemsetAsync(d_ws, 0, 65600, stream);
    hipMemsetAsync(d_out, 0, (size_t)out_size * sizeof(float), stream);

    snn_input_kernel<<<12, 256, 0, stream>>>(image, s_in_bits);

    for (int t = 0; t < TSTEPS; ++t) {
        snn_step_kernel<<<193, 512, 0, stream>>>(
            W1, W2, W3, m1, m2, m3,
            s_in_bits + t * 48,
            t ? s1_bits + (t - 1) * 128 : nullptr,
            t ? s2_bits + (t - 1) * 128 : nullptr,
            s1_bits + t * 128,
            s2_bits + t * 128,
            out + (t + 1) * 10);
    }
}